// Round 3
// baseline (1343.752 us; speedup 1.0000x reference)
//
#include <hip/hip_runtime.h>
#include <hip/hip_bf16.h>

// Sinkhorn via diagonal-scaling factorization:
//   M = exp(x)+eps;  repeat 100x: r = 1/(M c); c = 1/(M^T r);  y = diag(r) M diag(c)
// Mh (bf16) + MhT (bf16 transpose) staged in d_out. Persistent kernel, 256 WGs.
// Round 3: counter barriers replaced by tagged dataflow (per-block iteration tags,
// release-published; consumers poll tags then gather values via agent-scope atomics
// that bypass the non-coherent per-XCD L2s). No acquire anywhere -> no cache
// invalidates -> Mh/MhT stay L2-resident.

#define BATCH   16
#define NDIM    512
#define NNEL    (NDIM * NDIM)
#define ITERS   100
#define EPS_K   0.001f
#define WPB     16      // workgroups per batch
#define RPW     32      // rows (or cols) per workgroup
#define THREADS 512
#define CSTRIDE 64      // counter padding in ints (256 B)
#define TAGS    16      // tag ints per (slot,batch) block

__device__ __forceinline__ unsigned short f2bf(float f) {
  unsigned int u = __float_as_uint(f);
  u += 0x7fffu + ((u >> 16) & 1u);          // round-to-nearest-even
  return (unsigned short)(u >> 16);
}

// ---------------- Kernel 1: M = exp(x)+eps -> bf16 Mh and MhT, zero counters ---
__global__ __launch_bounds__(256) void prep_kernel(const float* __restrict__ x,
                                                   unsigned short* __restrict__ mh,
                                                   unsigned short* __restrict__ mht,
                                                   int* __restrict__ counters) {
  __shared__ float t[64][65];
  const int bid = blockIdx.x;
  if (bid == 0 && threadIdx.x < 32) counters[(int)threadIdx.x * CSTRIDE] = 0;
  const int b    = bid >> 6;          // 64 tiles of 64x64 per batch
  const int tile = bid & 63;
  const int tr   = (tile >> 3) << 6;
  const int tc   = (tile & 7) << 6;
  const int lx   = threadIdx.x & 63;
  const int ty   = threadIdx.x >> 6;  // 0..3
  const size_t base = (size_t)b * NNEL;
#pragma unroll
  for (int k = 0; k < 16; ++k) {
    int row = (k << 2) + ty;
    float v = expf(x[base + (size_t)(tr + row) * NDIM + tc + lx]) + EPS_K;
    mh[base + (size_t)(tr + row) * NDIM + tc + lx] = f2bf(v);
    t[row][lx] = v;
  }
  __syncthreads();
#pragma unroll
  for (int k = 0; k < 16; ++k) {
    int row = (k << 2) + ty;  // row of transposed tile = col of M
    mht[base + (size_t)(tc + row) * NDIM + tr + lx] = f2bf(t[lx][row]);
  }
}

// ---------------- epilogue-only cross-WG barrier (no acquire fence) -----------
__device__ __forceinline__ void wg_barrier(int* cnt, int target) {
  __syncthreads();
  if (threadIdx.x == 0) {
    __hip_atomic_fetch_add(cnt, 1, __ATOMIC_RELEASE, __HIP_MEMORY_SCOPE_AGENT);
    int guard = 0;
    while (__hip_atomic_load(cnt, __ATOMIC_RELAXED, __HIP_MEMORY_SCOPE_AGENT) < target) {
      __builtin_amdgcn_s_sleep(2);
      if (++guard > (1 << 22)) break;
    }
    asm volatile("" ::: "memory");
  }
  __syncthreads();
}

// one row (512 bf16) dotted with cc[8] held per-lane; full sum in all lanes
__device__ __forceinline__ float dot_row(const unsigned short* mrow, int lane,
                                         const float* cc) {
  uint4 v = *(const uint4*)(mrow + lane * 8);  // cols lane*8 .. lane*8+7, coalesced
  float p;
  p  = __uint_as_float(v.x << 16)         * cc[0];
  p += __uint_as_float(v.x & 0xffff0000u) * cc[1];
  p += __uint_as_float(v.y << 16)         * cc[2];
  p += __uint_as_float(v.y & 0xffff0000u) * cc[3];
  p += __uint_as_float(v.z << 16)         * cc[4];
  p += __uint_as_float(v.z & 0xffff0000u) * cc[5];
  p += __uint_as_float(v.w << 16)         * cc[6];
  p += __uint_as_float(v.w & 0xffff0000u) * cc[7];
#pragma unroll
  for (int o = 32; o > 0; o >>= 1) p += __shfl_xor(p, o, 64);
  return p;
}

// Poll the 16 per-block tags for one vector (lane L needs block L/4), then gather
// this lane's 8 contiguous floats. Tag-then-data: data loads issue only after the
// tag load returned `want` (control dependence), producer publishes tag with
// release -> values are committed at the coherence point before the tag is.
__device__ __forceinline__ void poll_gather8(const int* tags, const float* vals,
                                             int want, int lane, float* cc) {
  const int* tp = tags + (lane >> 2);
  int guard = 0;
  for (;;) {
    int tg = __hip_atomic_load(tp, __ATOMIC_RELAXED, __HIP_MEMORY_SCOPE_AGENT);
    if (__all(tg == want)) break;
    if (++guard > (1 << 22)) break;  // safety valve
  }
  const unsigned long long* vp = (const unsigned long long*)(vals + lane * 8);
#pragma unroll
  for (int k = 0; k < 4; ++k) {
    unsigned long long d =
        __hip_atomic_load(vp + k, __ATOMIC_RELAXED, __HIP_MEMORY_SCOPE_AGENT);
    cc[2 * k]     = __uint_as_float((unsigned int)(d & 0xffffffffu));
    cc[2 * k + 1] = __uint_as_float((unsigned int)(d >> 32));
  }
}

// epilogue gather: 4 floats at p0 and 4 at p1 (each within one 32-block)
__device__ __forceinline__ void poll_gather44(const int* tags, const float* vals,
                                              int want, int p0, int p1,
                                              float* a, float* bb) {
  const int* t0 = tags + (p0 >> 5);
  const int* t1 = tags + (p1 >> 5);
  int guard = 0;
  for (;;) {
    int g0 = __hip_atomic_load(t0, __ATOMIC_RELAXED, __HIP_MEMORY_SCOPE_AGENT);
    int g1 = __hip_atomic_load(t1, __ATOMIC_RELAXED, __HIP_MEMORY_SCOPE_AGENT);
    if (__all((g0 == want) && (g1 == want))) break;
    if (++guard > (1 << 22)) break;
  }
  const unsigned long long* v0 = (const unsigned long long*)(vals + p0);
  const unsigned long long* v1 = (const unsigned long long*)(vals + p1);
  unsigned long long d0 = __hip_atomic_load(v0,     __ATOMIC_RELAXED, __HIP_MEMORY_SCOPE_AGENT);
  unsigned long long d1 = __hip_atomic_load(v0 + 1, __ATOMIC_RELAXED, __HIP_MEMORY_SCOPE_AGENT);
  unsigned long long d2 = __hip_atomic_load(v1,     __ATOMIC_RELAXED, __HIP_MEMORY_SCOPE_AGENT);
  unsigned long long d3 = __hip_atomic_load(v1 + 1, __ATOMIC_RELAXED, __HIP_MEMORY_SCOPE_AGENT);
  a[0]  = __uint_as_float((unsigned int)(d0 & 0xffffffffu));
  a[1]  = __uint_as_float((unsigned int)(d0 >> 32));
  a[2]  = __uint_as_float((unsigned int)(d1 & 0xffffffffu));
  a[3]  = __uint_as_float((unsigned int)(d1 >> 32));
  bb[0] = __uint_as_float((unsigned int)(d2 & 0xffffffffu));
  bb[1] = __uint_as_float((unsigned int)(d2 >> 32));
  bb[2] = __uint_as_float((unsigned int)(d3 & 0xffffffffu));
  bb[3] = __uint_as_float((unsigned int)(d3 >> 32));
}

// ---------------- Kernel 2: persistent Sinkhorn, tagged dataflow --------------
__global__ __launch_bounds__(THREADS, 4) void sinkhorn_kernel(
    const unsigned short* __restrict__ mh, const unsigned short* __restrict__ mht,
    float* __restrict__ yout,
    int* rtag, int* ctag, float* rval, float* cval, int* counters) {
  __shared__ float rown[RPW];                               // final r values
  __shared__ alignas(16) unsigned short stage[RPW * NDIM];  // epilogue Mh rows
  const int wg   = blockIdx.x;
  const int b    = wg >> 4;
  const int sub  = wg & 15;
  const int i0   = sub * RPW;
  const int tid  = threadIdx.x;
  const int w    = tid >> 6;
  const int lane = tid & 63;
  int* gcnt = counters + 16 * CSTRIDE;
  const size_t mbase = (size_t)b * NNEL;
  float cc[8];
#pragma unroll
  for (int k = 0; k < 8; ++k) cc[k] = 1.0f;  // c0 = ones

#pragma unroll 1
  for (int t = 0; t < ITERS; ++t) {
    const int slot  = t & 1;
    const int pslot = slot ^ 1;                 // (t-1)&1 for t>=1
    // ---- row step: r = 1/(Mh c[t-1]) ----
    if (t > 0) {
      poll_gather8(ctag + (pslot * BATCH + b) * TAGS,
                   cval + (pslot * BATCH + b) * NDIM, t, lane, cc);
    }
    float rv[4];
#pragma unroll
    for (int rr = 0; rr < 4; ++rr) {
      int row = i0 + (w << 2) + rr;
      float s = dot_row(mh + mbase + (size_t)row * NDIM, lane, cc);
      rv[rr] = 1.0f / s;
    }
    if (lane == 0) {
      float* dst = rval + (slot * BATCH + b) * NDIM + i0 + (w << 2);
#pragma unroll
      for (int rr = 0; rr < 4; ++rr)
        __hip_atomic_store(dst + rr, rv[rr], __ATOMIC_RELAXED, __HIP_MEMORY_SCOPE_AGENT);
      if (t == ITERS - 1) {
#pragma unroll
        for (int rr = 0; rr < 4; ++rr) rown[(w << 2) + rr] = rv[rr];
      }
    }
    __syncthreads();  // all waves' value stores drained (vmcnt0 at barrier)
    if (tid == 0) {
      __hip_atomic_store(rtag + (slot * BATCH + b) * TAGS + sub, t + 1,
                         __ATOMIC_RELEASE, __HIP_MEMORY_SCOPE_AGENT);
    }
    // ---- col step: c = 1/(MhT r[t]) ----
    poll_gather8(rtag + (slot * BATCH + b) * TAGS,
                 rval + (slot * BATCH + b) * NDIM, t + 1, lane, cc);
    float cv[4];
#pragma unroll
    for (int rr = 0; rr < 4; ++rr) {
      int col = i0 + (w << 2) + rr;
      float s = dot_row(mht + mbase + (size_t)col * NDIM, lane, cc);
      cv[rr] = 1.0f / s;
    }
    if (lane == 0) {
      float* dst = cval + (slot * BATCH + b) * NDIM + i0 + (w << 2);
#pragma unroll
      for (int rr = 0; rr < 4; ++rr)
        __hip_atomic_store(dst + rr, cv[rr], __ATOMIC_RELAXED, __HIP_MEMORY_SCOPE_AGENT);
    }
    __syncthreads();
    if (tid == 0) {
      __hip_atomic_store(ctag + (slot * BATCH + b) * TAGS + sub, t + 1,
                         __ATOMIC_RELEASE, __HIP_MEMORY_SCOPE_AGENT);
    }
  }

  // ---- epilogue: y = diag(r) M diag(c); y overwrites Mh/MhT in d_out ----
  // stage this WG's 32 Mh rows to LDS before anyone overwrites them
  const uint4* src = (const uint4*)(mh + mbase + (size_t)i0 * NDIM);
  uint4* dst = (uint4*)stage;
#pragma unroll
  for (int k = 0; k < 4; ++k) dst[tid + k * THREADS] = src[tid + k * THREADS];
  // final c (iteration 99: slot 1, tag 100) at this lane's 8 output columns
  const int fslot = (ITERS - 1) & 1;
  float ca[4], cb[4];
  poll_gather44(ctag + (fslot * BATCH + b) * TAGS,
                cval + (fslot * BATCH + b) * NDIM, ITERS,
                lane * 4, 256 + lane * 4, ca, cb);
  // all 256 WGs must finish READING Mh/MhT before anyone WRITES y over them
  wg_barrier(gcnt, 256);
#pragma unroll
  for (int rr = 0; rr < 4; ++rr) {
    int rel = (w << 2) + rr;
    int row = i0 + rel;
    float rv = rown[rel];
    uint2 ma = *(const uint2*)(stage + rel * NDIM + lane * 4);
    uint2 mb = *(const uint2*)(stage + rel * NDIM + 256 + lane * 4);
    float4 oa, ob;
    oa.x = rv * __uint_as_float(ma.x << 16)         * ca[0];
    oa.y = rv * __uint_as_float(ma.x & 0xffff0000u) * ca[1];
    oa.z = rv * __uint_as_float(ma.y << 16)         * ca[2];
    oa.w = rv * __uint_as_float(ma.y & 0xffff0000u) * ca[3];
    ob.x = rv * __uint_as_float(mb.x << 16)         * cb[0];
    ob.y = rv * __uint_as_float(mb.x & 0xffff0000u) * cb[1];
    ob.z = rv * __uint_as_float(mb.y << 16)         * cb[2];
    ob.w = rv * __uint_as_float(mb.y & 0xffff0000u) * cb[3];
    *(float4*)(yout + mbase + (size_t)row * NDIM + lane * 4) = oa;
    *(float4*)(yout + mbase + (size_t)row * NDIM + 256 + lane * 4) = ob;
  }
}

extern "C" void kernel_launch(void* const* d_in, const int* in_sizes, int n_in,
                              void* d_out, int out_size, void* d_ws, size_t ws_size,
                              hipStream_t stream) {
  const float* x = (const float*)d_in[0];
  float* yout = (float*)d_out;
  unsigned short* mh  = (unsigned short*)d_out;            // 8 MiB bf16 M
  unsigned short* mht = mh + (size_t)BATCH * NNEL;         // 8 MiB bf16 M^T
  // workspace layout (tags poisoned 0xAAAAAAAA never match wanted tags 1..100)
  int*   rtag = (int*)d_ws;                                // 2*16*16 ints = 2 KB
  int*   ctag = rtag + 2 * BATCH * TAGS;                   // 2 KB
  float* rval = (float*)(ctag + 2 * BATCH * TAGS);         // 2*16*512 f = 64 KB
  float* cval = rval + 2 * BATCH * NDIM;                   // 64 KB
  int*   counters = (int*)(cval + 2 * BATCH * NDIM);       // 8 KB padded

  hipLaunchKernelGGL(prep_kernel, dim3(BATCH * 64), dim3(256), 0, stream,
                     x, mh, mht, counters);
  hipLaunchKernelGGL(sinkhorn_kernel, dim3(BATCH * WPB), dim3(THREADS), 0, stream,
                     mh, mht, yout, rtag, ctag, rval, cval, counters);
}

// Round 4
// 1233.643 us; speedup vs baseline: 1.0893x; 1.0893x over previous
//
#include <hip/hip_runtime.h>
#include <hip/hip_bf16.h>

// Sinkhorn via diagonal-scaling factorization:
//   M = exp(x)+eps;  repeat 100x: r = 1/(M c); c = 1/(M^T r);  y = diag(r) M diag(c)
// Round 4: self-validating dataflow. Iteration tag lives in the low 2 mantissa
// bits of every published r/c value (rel err 2^-22). Producers publish one
// dwordx4 sc1 store; consumers poll the data itself until all 8 of their floats
// carry tag t&3. No tag words, no counters, no __syncthreads in the main loop:
// the only cross-wave ordering is through the self-validating buffers.
// Chain per half-step = store visibility + poll detect (~2 LLC RTTs).

#define BATCH   16
#define NDIM    512
#define NNEL    (NDIM * NDIM)
#define ITERS   100
#define EPS_K   0.001f
#define WPB     16      // workgroups per batch
#define RPW     32      // rows (or cols) per workgroup
#define THREADS 512
#define CSTRIDE 64      // counter padding in ints (256 B)

typedef __attribute__((ext_vector_type(4))) unsigned int u32x4;
typedef __attribute__((ext_vector_type(4))) float        f32x4;

__device__ __forceinline__ unsigned short f2bf(float f) {
  unsigned int u = __float_as_uint(f);
  u += 0x7fffu + ((u >> 16) & 1u);          // round-to-nearest-even
  return (unsigned short)(u >> 16);
}

__device__ __forceinline__ float tagf(float v, unsigned tag) {
  return __uint_as_float((__float_as_uint(v) & ~3u) | tag);
}

// ---------------- Kernel 1: M = exp(x)+eps -> bf16 Mh and MhT, zero counters ---
__global__ __launch_bounds__(256) void prep_kernel(const float* __restrict__ x,
                                                   unsigned short* __restrict__ mh,
                                                   unsigned short* __restrict__ mht,
                                                   int* __restrict__ counters) {
  __shared__ float t[64][65];
  const int bid = blockIdx.x;
  if (bid == 0 && threadIdx.x < 32) counters[(int)threadIdx.x * CSTRIDE] = 0;
  const int b    = bid >> 6;          // 64 tiles of 64x64 per batch
  const int tile = bid & 63;
  const int tr   = (tile >> 3) << 6;
  const int tc   = (tile & 7) << 6;
  const int lx   = threadIdx.x & 63;
  const int ty   = threadIdx.x >> 6;  // 0..3
  const size_t base = (size_t)b * NNEL;
#pragma unroll
  for (int k = 0; k < 16; ++k) {
    int row = (k << 2) + ty;
    float v = expf(x[base + (size_t)(tr + row) * NDIM + tc + lx]) + EPS_K;
    mh[base + (size_t)(tr + row) * NDIM + tc + lx] = f2bf(v);
    t[row][lx] = v;
  }
  __syncthreads();
#pragma unroll
  for (int k = 0; k < 16; ++k) {
    int row = (k << 2) + ty;  // row of transposed tile = col of M
    mht[base + (size_t)(tc + row) * NDIM + tr + lx] = f2bf(t[lx][row]);
  }
}

// ---------------- epilogue-only cross-WG barrier ------------------------------
__device__ __forceinline__ void wg_barrier(int* cnt, int target) {
  __syncthreads();
  if (threadIdx.x == 0) {
    __hip_atomic_fetch_add(cnt, 1, __ATOMIC_RELEASE, __HIP_MEMORY_SCOPE_AGENT);
    int guard = 0;
    while (__hip_atomic_load(cnt, __ATOMIC_RELAXED, __HIP_MEMORY_SCOPE_AGENT) < target) {
      __builtin_amdgcn_s_sleep(2);
      if (++guard > (1 << 22)) break;
    }
    asm volatile("" ::: "memory");
  }
  __syncthreads();
}

// one row (512 bf16) dotted with cc[8] held per-lane; full sum in all lanes
__device__ __forceinline__ float dot_row(const unsigned short* mrow, int lane,
                                         const float* cc) {
  uint4 v = *(const uint4*)(mrow + lane * 8);  // cols lane*8 .. lane*8+7, coalesced
  float p;
  p  = __uint_as_float(v.x << 16)         * cc[0];
  p += __uint_as_float(v.x & 0xffff0000u) * cc[1];
  p += __uint_as_float(v.y << 16)         * cc[2];
  p += __uint_as_float(v.y & 0xffff0000u) * cc[3];
  p += __uint_as_float(v.z << 16)         * cc[4];
  p += __uint_as_float(v.z & 0xffff0000u) * cc[5];
  p += __uint_as_float(v.w << 16)         * cc[6];
  p += __uint_as_float(v.w & 0xffff0000u) * cc[7];
#pragma unroll
  for (int o = 32; o > 0; o >>= 1) p += __shfl_xor(p, o, 64);
  return p;
}

// poll 8 consecutive tagged floats at vp (32B aligned) until all carry `want`
__device__ __forceinline__ void poll8(const float* vp, unsigned want, float* cc) {
  u32x4 a, b;
  int guard = 0;
  for (;;) {
    asm volatile(
        "global_load_dwordx4 %0, %2, off sc1\n\t"
        "global_load_dwordx4 %1, %3, off sc1\n\t"
        "s_waitcnt vmcnt(0)"
        : "=&v"(a), "=&v"(b)
        : "v"(vp), "v"(vp + 4)
        : "memory");
    int ok = ((a[0] & 3u) == want) & ((a[1] & 3u) == want) &
             ((a[2] & 3u) == want) & ((a[3] & 3u) == want) &
             ((b[0] & 3u) == want) & ((b[1] & 3u) == want) &
             ((b[2] & 3u) == want) & ((b[3] & 3u) == want);
    if (__all(ok)) break;
    if (++guard > (1 << 20)) break;   // safety valve
    __builtin_amdgcn_s_sleep(1);
  }
  cc[0] = __uint_as_float(a[0]); cc[1] = __uint_as_float(a[1]);
  cc[2] = __uint_as_float(a[2]); cc[3] = __uint_as_float(a[3]);
  cc[4] = __uint_as_float(b[0]); cc[5] = __uint_as_float(b[1]);
  cc[6] = __uint_as_float(b[2]); cc[7] = __uint_as_float(b[3]);
}

// poll 4 consecutive tagged floats (epilogue c gather)
__device__ __forceinline__ void poll4(const float* vp, unsigned want, float* cc) {
  u32x4 a;
  int guard = 0;
  for (;;) {
    asm volatile(
        "global_load_dwordx4 %0, %1, off sc1\n\t"
        "s_waitcnt vmcnt(0)"
        : "=&v"(a) : "v"(vp) : "memory");
    int ok = ((a[0] & 3u) == want) & ((a[1] & 3u) == want) &
             ((a[2] & 3u) == want) & ((a[3] & 3u) == want);
    if (__all(ok)) break;
    if (++guard > (1 << 20)) break;
    __builtin_amdgcn_s_sleep(1);
  }
  cc[0] = __uint_as_float(a[0]); cc[1] = __uint_as_float(a[1]);
  cc[2] = __uint_as_float(a[2]); cc[3] = __uint_as_float(a[3]);
}

__device__ __forceinline__ void store4(float* dst, float x, float y, float z, float w) {
  f32x4 q; q[0] = x; q[1] = y; q[2] = z; q[3] = w;
  asm volatile("global_store_dwordx4 %0, %1, off sc1"
               :: "v"(dst), "v"(q) : "memory");
}

// ---------------- Kernel 2: persistent Sinkhorn, self-validating dataflow -----
__global__ __launch_bounds__(THREADS, 4) void sinkhorn_kernel(
    const unsigned short* __restrict__ mh, const unsigned short* __restrict__ mht,
    float* __restrict__ yout, float* rval, float* cval, int* counters) {
  __shared__ alignas(16) unsigned short stage[RPW * NDIM];  // epilogue Mh rows
  const int wg   = blockIdx.x;
  const int b    = wg >> 4;
  const int sub  = wg & 15;
  const int i0   = sub * RPW;
  const int tid  = threadIdx.x;
  const int w    = tid >> 6;
  const int lane = tid & 63;
  int* gcnt = counters + 16 * CSTRIDE;
  const size_t mbase = (size_t)b * NNEL;
  float cc[8];
#pragma unroll
  for (int k = 0; k < 8; ++k) cc[k] = 1.0f;  // c0 = ones
  float rfin[4];

#pragma unroll 1
  for (int t = 0; t < ITERS; ++t) {
    const int slot = t & 1;
    // ---- row step: r[t] = 1/(Mh c[t-1]) ----
    if (t > 0)
      poll8(cval + ((t - 1) & 1) * (BATCH * NDIM) + b * NDIM + lane * 8,
            (unsigned)((t - 1) & 3), cc);
    float rv[4];
#pragma unroll
    for (int rr = 0; rr < 4; ++rr) {
      int row = i0 + (w << 2) + rr;
      rv[rr] = 1.0f / dot_row(mh + mbase + (size_t)row * NDIM, lane, cc);
    }
    if (t == ITERS - 1) {
#pragma unroll
      for (int rr = 0; rr < 4; ++rr) rfin[rr] = rv[rr];
    }
    if (lane == 0)
      store4(rval + slot * (BATCH * NDIM) + b * NDIM + i0 + (w << 2),
             tagf(rv[0], t & 3), tagf(rv[1], t & 3),
             tagf(rv[2], t & 3), tagf(rv[3], t & 3));
    // ---- col step: c[t] = 1/(MhT r[t]) ----
    poll8(rval + slot * (BATCH * NDIM) + b * NDIM + lane * 8,
          (unsigned)(t & 3), cc);
    float cv[4];
#pragma unroll
    for (int rr = 0; rr < 4; ++rr) {
      int col = i0 + (w << 2) + rr;
      cv[rr] = 1.0f / dot_row(mht + mbase + (size_t)col * NDIM, lane, cc);
    }
    if (lane == 0)
      store4(cval + slot * (BATCH * NDIM) + b * NDIM + i0 + (w << 2),
             tagf(cv[0], t & 3), tagf(cv[1], t & 3),
             tagf(cv[2], t & 3), tagf(cv[3], t & 3));
  }

  // ---- epilogue: y = diag(r) M diag(c); y overwrites Mh/MhT in d_out ----
  __syncthreads();  // reconverge the WG (waves free-ran through the loop)
  const uint4* src = (const uint4*)(mh + mbase + (size_t)i0 * NDIM);
  uint4* dst = (uint4*)stage;
#pragma unroll
  for (int k = 0; k < 4; ++k) dst[tid + k * THREADS] = src[tid + k * THREADS];
  float ca[4], cb[4];
  const int fslot = (ITERS - 1) & 1;
  const unsigned fwant = (unsigned)((ITERS - 1) & 3);
  poll4(cval + fslot * (BATCH * NDIM) + b * NDIM + lane * 4, fwant, ca);
  poll4(cval + fslot * (BATCH * NDIM) + b * NDIM + 256 + lane * 4, fwant, cb);
  // all 256 WGs must finish READING Mh/MhT before anyone WRITES y over them
  wg_barrier(gcnt, 256);
#pragma unroll
  for (int rr = 0; rr < 4; ++rr) {
    int rel = (w << 2) + rr;
    int row = i0 + rel;
    float rv = rfin[rr];
    uint2 ma = *(const uint2*)(stage + rel * NDIM + lane * 4);
    uint2 mb = *(const uint2*)(stage + rel * NDIM + 256 + lane * 4);
    float4 oa, ob;
    oa.x = rv * __uint_as_float(ma.x << 16)         * ca[0];
    oa.y = rv * __uint_as_float(ma.x & 0xffff0000u) * ca[1];
    oa.z = rv * __uint_as_float(ma.y << 16)         * ca[2];
    oa.w = rv * __uint_as_float(ma.y & 0xffff0000u) * ca[3];
    ob.x = rv * __uint_as_float(mb.x << 16)         * cb[0];
    ob.y = rv * __uint_as_float(mb.x & 0xffff0000u) * cb[1];
    ob.z = rv * __uint_as_float(mb.y << 16)         * cb[2];
    ob.w = rv * __uint_as_float(mb.y & 0xffff0000u) * cb[3];
    *(float4*)(yout + mbase + (size_t)row * NDIM + lane * 4) = oa;
    *(float4*)(yout + mbase + (size_t)row * NDIM + 256 + lane * 4) = ob;
  }
}

extern "C" void kernel_launch(void* const* d_in, const int* in_sizes, int n_in,
                              void* d_out, int out_size, void* d_ws, size_t ws_size,
                              hipStream_t stream) {
  const float* x = (const float*)d_in[0];
  float* yout = (float*)d_out;
  unsigned short* mh  = (unsigned short*)d_out;            // 8 MiB bf16 M
  unsigned short* mht = mh + (size_t)BATCH * NNEL;         // 8 MiB bf16 M^T
  // workspace: tagged value buffers (poison 0xAAAAAAAA has tag bits 2; all
  // first-touch polls want tags 0/1/3, and want==2 polls are provably >= 2
  // rounds after slot initialization), then the epilogue barrier counter.
  float* rval = (float*)d_ws;                              // 2*16*512 f = 64 KB
  float* cval = rval + 2 * BATCH * NDIM;                   // 64 KB
  int*   counters = (int*)(cval + 2 * BATCH * NDIM);       // ~4.3 KB padded

  hipLaunchKernelGGL(prep_kernel, dim3(BATCH * 64), dim3(256), 0, stream,
                     x, mh, mht, counters);
  hipLaunchKernelGGL(sinkhorn_kernel, dim3(BATCH * WPB), dim3(THREADS), 0, stream,
                     mh, mht, yout, rval, cval, counters);
}